// Round 7
// baseline (729.608 us; speedup 1.0000x reference)
//
#include <hip/hip_runtime.h>
#include <hip/hip_bf16.h>
#include <cstdint>

// ---------------------------------------------------------------------------
// 3-layer GCN on MI355X — bf16 feature pipeline, f32 accumulate.
//   k_prep : x->bf16 | W->Wt bf16 | zero cnt, A zero-row, ovfn
//   k_cnt  : pos[e] = atomicAdd(cnt[dst[e]], 1)        (atomic pass, minimal)
//   k_gemm : R = bf16(xb@Wr + br)                      (residual)
//   k_scat : atomic-free scatter: rank<32 -> epk[d*32+rank]=src else ovf
//   k_aux  : dinv=rsqrt(cnt+1); pad epk slots [min(c,32), ceil8) with N.
//   A  = bf16( dinv * (xb @ W0) )    (dinv folded into GEMM epilogue)
//   H0 = bf16( relu(dinv_d * (A[self] + sum_src A[src]) + b0) + R )
//   ... layers 1,2 same; layer 2 writes f32 to d_out.
//
// Lessons: R10-12 — atomics execute memory-side regardless of scope; k_agg
// FETCH == 8 XCD x 25.6 MB (compulsory). R15 — fusing the epk scatter INTO
// the atomic pass backfired (WRITE 56->96 MB, 67->120 us; time tracks
// memory-side write traffic ~0.8 GB/ms). R16 (this):
//  (1) split: k_cnt (proven 67us shape) + k_scat (no RMW wall).
//  (2) k_agg: TWO independent nodes per 16-lane group (8 nodes/wave) —
//      independent chains defeat the compiler's re-serialization (R12's
//      single-chain deepening collapsed back to VGPR 36). Branch-free tails:
//      shorter stream clamps epk indices to zero-row N (cache-hot, adds 0).
// ---------------------------------------------------------------------------

#define WS_ALIGN(x) (((x) + 255) & ~(size_t)255)

typedef __bf16 bf16x8 __attribute__((ext_vector_type(8)));
typedef float  floatx4 __attribute__((ext_vector_type(4)));

static __device__ __forceinline__ float bf_lo(unsigned u) {
  return __builtin_bit_cast(float, u << 16);
}
static __device__ __forceinline__ float bf_hi(unsigned u) {
  return __builtin_bit_cast(float, u & 0xffff0000u);
}
// f32 -> bf16 round-to-nearest-even (finite inputs only)
static __device__ __forceinline__ unsigned short f2bs(float f) {
  unsigned u = __builtin_bit_cast(unsigned, f);
  return (unsigned short)((u + 0x7fffu + ((u >> 16) & 1u)) >> 16);
}
static __device__ __forceinline__ unsigned pack2(float a, float b) {
  return (unsigned)f2bs(a) | ((unsigned)f2bs(b) << 16);
}

// ------- prep: zero cnt | x->bf16 | W->Wt bf16 | zero A row N | ovfn=0 -----
__global__ void k_prep(const float* __restrict__ x, unsigned* __restrict__ xb, int n4,
                       int* __restrict__ cnt, int n,
                       const float* __restrict__ W0, const float* __restrict__ W1,
                       const float* __restrict__ W2, const float* __restrict__ Wr,
                       unsigned short* __restrict__ Wt,
                       unsigned short* __restrict__ A, int* __restrict__ ovfn,
                       int zb, int xbn) {
  int b = blockIdx.x;
  if (b < zb) {
    int i = b * 256 + threadIdx.x;
    if (i < n) cnt[i] = 0;
  } else if (b < zb + xbn) {
    int i = (b - zb) * 256 + threadIdx.x;
    if (i < n4) {
      float4 v = ((const float4*)x)[i];
      uint2 o;
      o.x = pack2(v.x, v.y);
      o.y = pack2(v.z, v.w);
      ((uint2*)xb)[i] = o;
    }
  } else {
    int wb = b - zb - xbn;            // 0..256
    if (wb < 256) {
      int mat = wb >> 6, blk = wb & 63;
      const float* W = mat == 0 ? W0 : mat == 1 ? W1 : mat == 2 ? W2 : Wr;
      unsigned short* T = Wt + (size_t)mat * 16384;
      int i = blk * 256 + threadIdx.x;  // i = k*128 + nn, coalesced read
      int k = i >> 7, nn = i & 127;
      T[nn * 128 + k] = f2bs(W[i]);
    } else {
      // zero row N of A (pad-gather target) + overflow counter
      if (threadIdx.x < 16) {
        uint4 z; z.x = 0; z.y = 0; z.z = 0; z.w = 0;
        ((uint4*)(A + (size_t)n * 128))[threadIdx.x] = z;
      }
      if (threadIdx.x == 16) *ovfn = 0;
    }
  }
}

// ---- atomic pass only (proven shape): rank per edge, coalesced pos write ----
__global__ void k_cnt(const int* __restrict__ dstv, int E,
                      int* __restrict__ cnt, int* __restrict__ pos) {
  int e = blockIdx.x * blockDim.x + threadIdx.x;
  if (e < E) pos[e] = atomicAdd(&cnt[dstv[e]], 1);
}

// ---- atomic-free scatter (overflow path keeps its rare atomic) -------------
__global__ void k_scat(const int* __restrict__ srcv, const int* __restrict__ dstv,
                       const int* __restrict__ pos, int E,
                       int* __restrict__ epk, int2* __restrict__ ovf,
                       int* __restrict__ ovfn) {
  int e = blockIdx.x * blockDim.x + threadIdx.x;
  if (e < E) {
    int s = srcv[e], d = dstv[e];
    int r = pos[e];
    if (r < 32) {
      epk[(size_t)d * 32 + r] = s;
    } else {
      int o = atomicAdd(ovfn, 1);
      if (o < E) {                     // defensive clamp (can't exceed)
        int2 t; t.x = s; t.y = d;
        ovf[o] = t;
      }
    }
  }
}

// --------- aux: dinv from degree; pad epk slots with zero-row index --------
__global__ void k_aux(const int* __restrict__ cnt, float* __restrict__ dinv,
                      int* __restrict__ epk, int n) {
  int i = blockIdx.x * 256 + threadIdx.x;
  if (i < n) {
    int c = cnt[i];
    dinv[i] = rsqrtf((float)(c + 1));   // +1 = self-loop; always > 0
    int cm = c < 32 ? c : 32;
    int cp = (cm + 7) & ~7;
    for (int k = cm; k < cp; k++) epk[(size_t)i * 32 + k] = n;  // zero row
  }
}

// ---------------- bf16 MFMA GEMM: Y = bf16( dv[r] * (Xb@W) + bias ) --------
// Wt pre-transposed [n][k] bf16, staged in 32 KB LDS. Block = 256 thr =
// 4 waves; each wave computes a 16-row x 128-col strip with 32 MFMAs.
// Layouts (verified, learn_hip m89/m120): A[m=lane&15][k=quad*8+j],
// B[k=quad*8+j][n=lane&15], C/D col=lane&15 row=quad*4+reg.
__global__ __launch_bounds__(256, 2) void k_gemm_mfma(
    const unsigned short* __restrict__ Xb,
    const unsigned short* __restrict__ Wt,
    const float* __restrict__ bias,
    const float* __restrict__ dv,
    unsigned short* __restrict__ Y,
    int n) {
  __shared__ unsigned short sWt[128 * 128];
  {
    const uint4* s4 = (const uint4*)Wt;
    uint4* d4 = (uint4*)sWt;
    for (int i = threadIdx.x; i < 2048; i += 256) d4[i] = s4[i];
  }
  __syncthreads();

  const int lane = threadIdx.x & 63;
  const int wave = threadIdx.x >> 6;
  const int l15 = lane & 15;
  const int quad = lane >> 4;
  const int rbase = blockIdx.x * 64 + wave * 16;

  const bf16x8* sW8 = (const bf16x8*)sWt;
  bf16x8 b[8][4];
#pragma unroll
  for (int ct = 0; ct < 8; ct++)
#pragma unroll
    for (int kc = 0; kc < 4; kc++)
      b[ct][kc] = sW8[(ct * 16 + l15) * 16 + kc * 4 + quad];

  int row = rbase + l15;
  row = row < n ? row : n - 1;
  const bf16x8* X8 = (const bf16x8*)Xb;
  bf16x8 a[4];
#pragma unroll
  for (int kc = 0; kc < 4; kc++)
    a[kc] = X8[(size_t)row * 16 + kc * 4 + quad];

  floatx4 acc[8];
#pragma unroll
  for (int ct = 0; ct < 8; ct++) acc[ct] = (floatx4){0.f, 0.f, 0.f, 0.f};

#pragma unroll
  for (int kc = 0; kc < 4; kc++)
#pragma unroll
    for (int ct = 0; ct < 8; ct++)
      acc[ct] = __builtin_amdgcn_mfma_f32_16x16x32_bf16(a[kc], b[ct][kc], acc[ct], 0, 0, 0);

  const int orow = rbase + quad * 4;
  float4 dvv;
  dvv.x = 1.f; dvv.y = 1.f; dvv.z = 1.f; dvv.w = 1.f;
  if (dv) {
    int od = orow < n ? orow : 0;      // orow is 4-aligned, n % 4 == 0
    dvv = *(const float4*)(dv + od);
  }
#pragma unroll
  for (int ct = 0; ct < 8; ct++) {
    const int c = ct * 16 + l15;
    const float bv = bias ? bias[c] : 0.f;
#pragma unroll
    for (int r4 = 0; r4 < 4; r4++) {
      int r = orow + r4;
      float dm = r4 == 0 ? dvv.x : r4 == 1 ? dvv.y : r4 == 2 ? dvv.z : dvv.w;
      if (r < n) Y[(size_t)r * 128 + c] = f2bs(acc[ct][r4] * dm + bv);
    }
  }
}

// ---------------- aggregation ----------------
// EIGHT nodes per wave: each 16-lane quarter-wave owns TWO nodes with
// independent accumulator chains — the two gather streams interleave in
// the scheduler, doubling rows in flight (R12's single-chain deepening was
// re-serialized by the compiler). Branch-free: the shorter stream's tail
// clamps epk indices to zero-row N (cache-hot, contributes 0).
static __device__ __forceinline__ void add8(uint4 h, float* a) {
  a[0] += bf_lo(h.x); a[1] += bf_hi(h.x);
  a[2] += bf_lo(h.y); a[3] += bf_hi(h.y);
  a[4] += bf_lo(h.z); a[5] += bf_hi(h.z);
  a[6] += bf_lo(h.w); a[7] += bf_hi(h.w);
}

__global__ __launch_bounds__(256, 4) void k_agg(
    const uint4* __restrict__ H,         // bf16x8 per lane [(n+1)*16], prescaled
    const int* __restrict__ cnt,
    const int* __restrict__ epk,
    const float* __restrict__ dinv,
    const float* __restrict__ bias,
    const uint4* __restrict__ resid,     // bf16x8 or null
    uint4* __restrict__ outb,            // bf16 out (layers 0,1) or null
    float4* __restrict__ outf,           // f32 out (layer 2) or null
    const int2* __restrict__ ovf, const int* __restrict__ ovfn,
    int n, int Ecap) {
  int grp = blockIdx.x * 16 + (threadIdx.x >> 4);
  int l = threadIdx.x & 15;
  int n0 = grp * 2;
  int n1 = n0 + 1;
  if (n0 >= n) return;
  bool has1 = (n1 < n);

  int t0 = cnt[n0];
  int t1 = has1 ? cnt[n1] : 0;
  int c0 = t0 < 32 ? t0 : 32;
  int c1 = t1 < 32 ? t1 : 32;
  int p0 = (c0 + 7) & ~7;
  int p1 = has1 ? ((c1 + 7) & ~7) : 0;

  uint4 hv0 = H[(size_t)n0 * 16 + l];            // self terms (prescaled)
  uint4 hv1 = H[(size_t)(has1 ? n1 : n) * 16 + l];   // row n = zero row

  float a0[8], a1[8];
  a0[0] = bf_lo(hv0.x); a0[1] = bf_hi(hv0.x);
  a0[2] = bf_lo(hv0.y); a0[3] = bf_hi(hv0.y);
  a0[4] = bf_lo(hv0.z); a0[5] = bf_hi(hv0.z);
  a0[6] = bf_lo(hv0.w); a0[7] = bf_hi(hv0.w);
  a1[0] = bf_lo(hv1.x); a1[1] = bf_hi(hv1.x);
  a1[2] = bf_lo(hv1.y); a1[3] = bf_hi(hv1.y);
  a1[4] = bf_lo(hv1.z); a1[5] = bf_hi(hv1.z);
  a1[6] = bf_lo(hv1.w); a1[7] = bf_hi(hv1.w);

  const int4* q0 = (const int4*)(epk + (size_t)n0 * 32);
  const int4* q1 = (const int4*)(epk + (size_t)(has1 ? n1 : n0) * 32);
  int4 zq; zq.x = n; zq.y = n; zq.z = n; zq.w = n;   // zero-row indices

  int jm = p0 > p1 ? p0 : p1;
  for (int j = 0; j < jm; j += 8) {
    bool d0 = j < p0, d1 = j < p1;
    int4 e0a = d0 ? q0[j >> 2] : zq;
    int4 e0b = d0 ? q0[(j >> 2) + 1] : zq;
    int4 e1a = d1 ? q1[j >> 2] : zq;
    int4 e1b = d1 ? q1[(j >> 2) + 1] : zq;
    uint4 h00 = H[(size_t)(unsigned)e0a.x * 16 + l];
    uint4 h01 = H[(size_t)(unsigned)e0a.y * 16 + l];
    uint4 h02 = H[(size_t)(unsigned)e0a.z * 16 + l];
    uint4 h03 = H[(size_t)(unsigned)e0a.w * 16 + l];
    uint4 h10 = H[(size_t)(unsigned)e1a.x * 16 + l];
    uint4 h11 = H[(size_t)(unsigned)e1a.y * 16 + l];
    uint4 h12 = H[(size_t)(unsigned)e1a.z * 16 + l];
    uint4 h13 = H[(size_t)(unsigned)e1a.w * 16 + l];
    uint4 h04 = H[(size_t)(unsigned)e0b.x * 16 + l];
    uint4 h05 = H[(size_t)(unsigned)e0b.y * 16 + l];
    uint4 h06 = H[(size_t)(unsigned)e0b.z * 16 + l];
    uint4 h07 = H[(size_t)(unsigned)e0b.w * 16 + l];
    uint4 h14 = H[(size_t)(unsigned)e1b.x * 16 + l];
    uint4 h15 = H[(size_t)(unsigned)e1b.y * 16 + l];
    uint4 h16 = H[(size_t)(unsigned)e1b.z * 16 + l];
    uint4 h17 = H[(size_t)(unsigned)e1b.w * 16 + l];
    add8(h00, a0); add8(h10, a1);
    add8(h01, a0); add8(h11, a1);
    add8(h02, a0); add8(h12, a1);
    add8(h03, a0); add8(h13, a1);
    add8(h04, a0); add8(h14, a1);
    add8(h05, a0); add8(h15, a1);
    add8(h06, a0); add8(h16, a1);
    add8(h07, a0); add8(h17, a1);
  }

  if (t0 > 32 || t1 > 32) {              // rare: walk overflow list
    int no = *ovfn;
    no = no < Ecap ? no : Ecap;          // defensive clamp
    for (int i = 0; i < no; i++) {
      int2 t = ovf[i];
      if (t0 > 32 && t.y == n0) add8(H[(size_t)(unsigned)t.x * 16 + l], a0);
      if (has1 && t1 > 32 && t.y == n1) add8(H[(size_t)(unsigned)t.x * 16 + l], a1);
    }
  }

  float4 bl = ((const float4*)bias)[l * 2];
  float4 bh = ((const float4*)bias)[l * 2 + 1];
  float dn0 = dinv[n0];
  float dn1 = has1 ? dinv[n1] : 0.f;

  a0[0] = fmaxf(fmaf(a0[0], dn0, bl.x), 0.f); a0[1] = fmaxf(fmaf(a0[1], dn0, bl.y), 0.f);
  a0[2] = fmaxf(fmaf(a0[2], dn0, bl.z), 0.f); a0[3] = fmaxf(fmaf(a0[3], dn0, bl.w), 0.f);
  a0[4] = fmaxf(fmaf(a0[4], dn0, bh.x), 0.f); a0[5] = fmaxf(fmaf(a0[5], dn0, bh.y), 0.f);
  a0[6] = fmaxf(fmaf(a0[6], dn0, bh.z), 0.f); a0[7] = fmaxf(fmaf(a0[7], dn0, bh.w), 0.f);
  a1[0] = fmaxf(fmaf(a1[0], dn1, bl.x), 0.f); a1[1] = fmaxf(fmaf(a1[1], dn1, bl.y), 0.f);
  a1[2] = fmaxf(fmaf(a1[2], dn1, bl.z), 0.f); a1[3] = fmaxf(fmaf(a1[3], dn1, bl.w), 0.f);
  a1[4] = fmaxf(fmaf(a1[4], dn1, bh.x), 0.f); a1[5] = fmaxf(fmaf(a1[5], dn1, bh.y), 0.f);
  a1[6] = fmaxf(fmaf(a1[6], dn1, bh.z), 0.f); a1[7] = fmaxf(fmaf(a1[7], dn1, bh.w), 0.f);

  if (resid) {
    uint4 r0 = resid[(size_t)n0 * 16 + l];
    a0[0] += bf_lo(r0.x); a0[1] += bf_hi(r0.x);
    a0[2] += bf_lo(r0.y); a0[3] += bf_hi(r0.y);
    a0[4] += bf_lo(r0.z); a0[5] += bf_hi(r0.z);
    a0[6] += bf_lo(r0.w); a0[7] += bf_hi(r0.w);
    if (has1) {
      uint4 r1 = resid[(size_t)n1 * 16 + l];
      a1[0] += bf_lo(r1.x); a1[1] += bf_hi(r1.x);
      a1[2] += bf_lo(r1.y); a1[3] += bf_hi(r1.y);
      a1[4] += bf_lo(r1.z); a1[5] += bf_hi(r1.z);
      a1[6] += bf_lo(r1.w); a1[7] += bf_hi(r1.w);
    }
  }
  if (outb) {
    uint4 o0;
    o0.x = pack2(a0[0], a0[1]); o0.y = pack2(a0[2], a0[3]);
    o0.z = pack2(a0[4], a0[5]); o0.w = pack2(a0[6], a0[7]);
    outb[(size_t)n0 * 16 + l] = o0;
    if (has1) {
      uint4 o1;
      o1.x = pack2(a1[0], a1[1]); o1.y = pack2(a1[2], a1[3]);
      o1.z = pack2(a1[4], a1[5]); o1.w = pack2(a1[6], a1[7]);
      outb[(size_t)n1 * 16 + l] = o1;
    }
  } else {
    float4 o0a; o0a.x = a0[0]; o0a.y = a0[1]; o0a.z = a0[2]; o0a.w = a0[3];
    float4 o0b; o0b.x = a0[4]; o0b.y = a0[5]; o0b.z = a0[6]; o0b.w = a0[7];
    outf[(size_t)n0 * 32 + l * 2] = o0a;
    outf[(size_t)n0 * 32 + l * 2 + 1] = o0b;
    if (has1) {
      float4 o1a; o1a.x = a1[0]; o1a.y = a1[1]; o1a.z = a1[2]; o1a.w = a1[3];
      float4 o1b; o1b.x = a1[4]; o1b.y = a1[5]; o1b.z = a1[6]; o1b.w = a1[7];
      outf[(size_t)n1 * 32 + l * 2] = o1a;
      outf[(size_t)n1 * 32 + l * 2 + 1] = o1b;
    }
  }
}

extern "C" void kernel_launch(void* const* d_in, const int* in_sizes, int n_in,
                              void* d_out, int out_size, void* d_ws, size_t ws_size,
                              hipStream_t stream) {
  const float* x  = (const float*)d_in[0];
  const int* edges = (const int*)d_in[1];
  const float* W0 = (const float*)d_in[2];
  const float* b0 = (const float*)d_in[3];
  const float* W1 = (const float*)d_in[4];
  const float* b1 = (const float*)d_in[5];
  const float* W2 = (const float*)d_in[6];
  const float* b2 = (const float*)d_in[7];
  const float* Wr = (const float*)d_in[8];
  const float* br = (const float*)d_in[9];

  int N = in_sizes[0] / 128;
  int E = in_sizes[1] / 2;
  const int* src = edges;
  const int* dst = edges + E;

  char* ws = (char*)d_ws;
  size_t off = 0;
  auto alloc = [&](size_t bytes) -> void* {
    void* p = ws + off; off = WS_ALIGN(off + bytes); return p;
  };
  int*   cnt  = (int*)  alloc((size_t)N * 4);
  float* dinv = (float*)alloc((size_t)N * 4);
  int*   ovfn = (int*)  alloc(256);
  int2*  ovf  = (int2*) alloc((size_t)E * 8);
  int*   epk  = (int*)  alloc((size_t)N * 32 * 4);           // fixed-stride CSR
  unsigned short* xb = (unsigned short*)alloc((size_t)N * 128 * 2);
  unsigned short* Wt = (unsigned short*)alloc((size_t)4 * 16384 * 2);
  unsigned short* A  = (unsigned short*)alloc(((size_t)N + 1) * 128 * 2); // +zero row
  unsigned short* Hb = (unsigned short*)alloc((size_t)N * 128 * 2);
  unsigned short* R  = (unsigned short*)alloc((size_t)N * 128 * 2);
  int* pos = (int*)A;   // pos[E] lives only between k_cnt and k_scat; A is
                        // first written by GEMM0, which runs after k_scat.
  (void)ws_size; (void)n_in; (void)out_size;

  // ---- prep ----
  int n4 = N * 128 / 4;
  int zb = (N + 255) / 256;
  int xbn = (n4 + 255) / 256;
  k_prep<<<zb + xbn + 257, 256, 0, stream>>>(x, (unsigned*)xb, n4, cnt, N,
                                             W0, W1, W2, Wr, Wt, A, ovfn, zb, xbn);

  // ---- CSR build: atomic pass | residual GEMM | atomic-free scatter ----
  int gb = (N + 63) / 64;
  int eb = (E + 255) / 256;
  unsigned short* Wt0 = Wt;
  unsigned short* Wt1 = Wt + 16384;
  unsigned short* Wt2 = Wt + 2 * 16384;
  unsigned short* Wtr = Wt + 3 * 16384;
  k_cnt<<<eb, 256, 0, stream>>>(dst, E, cnt, pos);
  k_gemm_mfma<<<gb, 256, 0, stream>>>(xb, Wtr, br, nullptr, R, N);   // residual
  k_scat<<<eb, 256, 0, stream>>>(src, dst, pos, E, epk, ovf, ovfn);
  k_aux<<<(N + 255) / 256, 256, 0, stream>>>(cnt, dinv, epk, N);

  // ---- GCN layers (GEMMs prescale rows by dinv) ----
  int ab = (N + 31) / 32;   // 32 nodes per 256-thread block (2 per 16-lane grp)

  k_gemm_mfma<<<gb, 256, 0, stream>>>(xb, Wt0, nullptr, dinv, A, N);
  k_agg<<<ab, 256, 0, stream>>>((const uint4*)A, cnt, epk, dinv, b0,
                                (const uint4*)R, (uint4*)Hb, nullptr, ovf, ovfn, N, E);
  k_gemm_mfma<<<gb, 256, 0, stream>>>(Hb, Wt1, nullptr, dinv, A, N);
  k_agg<<<ab, 256, 0, stream>>>((const uint4*)A, cnt, epk, dinv, b1,
                                nullptr, (uint4*)R, nullptr, ovf, ovfn, N, E);
  k_gemm_mfma<<<gb, 256, 0, stream>>>(R, Wt2, nullptr, dinv, A, N);
  k_agg<<<ab, 256, 0, stream>>>((const uint4*)A, cnt, epk, dinv, b2,
                                nullptr, nullptr, (float4*)d_out, ovf, ovfn, N, E);
}

// Round 8
// 559.169 us; speedup vs baseline: 1.3048x; 1.3048x over previous
//
#include <hip/hip_runtime.h>
#include <hip/hip_bf16.h>
#include <cstdint>

// ---------------------------------------------------------------------------
// 3-layer GCN on MI355X — bf16 feature pipeline, f32 accumulate.
//   k_prep : x->bf16 | W->Wt bf16 | zero cnt, A zero-row, ovfn
//   k_cnt  : pos[e] = atomicAdd(cnt[dst[e]], 1)        (atomic pass, minimal)
//   k_gemm : R = bf16(xb@Wr + br)                      (residual)
//   k_scat : atomic-free scatter: rank<32 -> epk[d*32+rank]=src else ovf
//   k_aux  : dinv=rsqrt(cnt+1); pad epk slots [min(c,32), ceil8) with N.
//   A  = bf16( dinv * (xb @ W0) )    (dinv folded into GEMM epilogue)
//   H0 = bf16( relu(dinv_d * (A[self] + sum_src A[src]) + b0) + R )
//   ... layers 1,2 same; layer 2 writes f32 to d_out.
//
// Lessons: R10-12 — atomics execute memory-side regardless of scope; k_agg
// FETCH == 8 XCD x 25.6 MB (compulsory); single-chain ILP deepening gets
// re-serialized (VGPR stays 36). R15 — scatter fused into the atomic pass
// doubles memory-side write traffic (67 -> 120 us). R16 — two-node k_agg
// SPILLED (VGPR 64, WRITE 25->229 MB, 65->145 us): both ILP-widening paths
// are closed; k_agg's 8-deep/VGPR-36 form is its practical optimum. FINAL
// k_agg form — do not restructure. R17 (this): revert k_agg to R15 exact;
// keep k_cnt/k_scat split; NEW: GEMM drops the LDS bounce — Wt is
// L2-resident (1563 blocks share 128 KB), B-fragments load directly from
// global with identical indexing (deletes 2048 LDS ld/st + barrier/block).
// ---------------------------------------------------------------------------

#define WS_ALIGN(x) (((x) + 255) & ~(size_t)255)

typedef __bf16 bf16x8 __attribute__((ext_vector_type(8)));
typedef float  floatx4 __attribute__((ext_vector_type(4)));

static __device__ __forceinline__ float bf_lo(unsigned u) {
  return __builtin_bit_cast(float, u << 16);
}
static __device__ __forceinline__ float bf_hi(unsigned u) {
  return __builtin_bit_cast(float, u & 0xffff0000u);
}
// f32 -> bf16 round-to-nearest-even (finite inputs only)
static __device__ __forceinline__ unsigned short f2bs(float f) {
  unsigned u = __builtin_bit_cast(unsigned, f);
  return (unsigned short)((u + 0x7fffu + ((u >> 16) & 1u)) >> 16);
}
static __device__ __forceinline__ unsigned pack2(float a, float b) {
  return (unsigned)f2bs(a) | ((unsigned)f2bs(b) << 16);
}

// ------- prep: zero cnt | x->bf16 | W->Wt bf16 | zero A row N | ovfn=0 -----
__global__ void k_prep(const float* __restrict__ x, unsigned* __restrict__ xb, int n4,
                       int* __restrict__ cnt, int n,
                       const float* __restrict__ W0, const float* __restrict__ W1,
                       const float* __restrict__ W2, const float* __restrict__ Wr,
                       unsigned short* __restrict__ Wt,
                       unsigned short* __restrict__ A, int* __restrict__ ovfn,
                       int zb, int xbn) {
  int b = blockIdx.x;
  if (b < zb) {
    int i = b * 256 + threadIdx.x;
    if (i < n) cnt[i] = 0;
  } else if (b < zb + xbn) {
    int i = (b - zb) * 256 + threadIdx.x;
    if (i < n4) {
      float4 v = ((const float4*)x)[i];
      uint2 o;
      o.x = pack2(v.x, v.y);
      o.y = pack2(v.z, v.w);
      ((uint2*)xb)[i] = o;
    }
  } else {
    int wb = b - zb - xbn;            // 0..256
    if (wb < 256) {
      int mat = wb >> 6, blk = wb & 63;
      const float* W = mat == 0 ? W0 : mat == 1 ? W1 : mat == 2 ? W2 : Wr;
      unsigned short* T = Wt + (size_t)mat * 16384;
      int i = blk * 256 + threadIdx.x;  // i = k*128 + nn, coalesced read
      int k = i >> 7, nn = i & 127;
      T[nn * 128 + k] = f2bs(W[i]);
    } else {
      // zero row N of A (pad-gather target) + overflow counter
      if (threadIdx.x < 16) {
        uint4 z; z.x = 0; z.y = 0; z.z = 0; z.w = 0;
        ((uint4*)(A + (size_t)n * 128))[threadIdx.x] = z;
      }
      if (threadIdx.x == 16) *ovfn = 0;
    }
  }
}

// ---- atomic pass only (proven shape): rank per edge, coalesced pos write ----
__global__ void k_cnt(const int* __restrict__ dstv, int E,
                      int* __restrict__ cnt, int* __restrict__ pos) {
  int e = blockIdx.x * blockDim.x + threadIdx.x;
  if (e < E) pos[e] = atomicAdd(&cnt[dstv[e]], 1);
}

// ---- atomic-free scatter (overflow path keeps its rare atomic) -------------
__global__ void k_scat(const int* __restrict__ srcv, const int* __restrict__ dstv,
                       const int* __restrict__ pos, int E,
                       int* __restrict__ epk, int2* __restrict__ ovf,
                       int* __restrict__ ovfn) {
  int e = blockIdx.x * blockDim.x + threadIdx.x;
  if (e < E) {
    int s = srcv[e], d = dstv[e];
    int r = pos[e];
    if (r < 32) {
      epk[(size_t)d * 32 + r] = s;
    } else {
      int o = atomicAdd(ovfn, 1);
      if (o < E) {                     // defensive clamp (can't exceed)
        int2 t; t.x = s; t.y = d;
        ovf[o] = t;
      }
    }
  }
}

// --------- aux: dinv from degree; pad epk slots with zero-row index --------
__global__ void k_aux(const int* __restrict__ cnt, float* __restrict__ dinv,
                      int* __restrict__ epk, int n) {
  int i = blockIdx.x * 256 + threadIdx.x;
  if (i < n) {
    int c = cnt[i];
    dinv[i] = rsqrtf((float)(c + 1));   // +1 = self-loop; always > 0
    int cm = c < 32 ? c : 32;
    int cp = (cm + 7) & ~7;
    for (int k = cm; k < cp; k++) epk[(size_t)i * 32 + k] = n;  // zero row
  }
}

// ---------------- bf16 MFMA GEMM: Y = bf16( dv[r] * (Xb@W) + bias ) --------
// Wt pre-transposed [n][k] bf16. NO LDS bounce: Wt is L2-resident (all
// blocks share the same 128 KB), B-fragments load directly from global
// with the identical indexing the LDS read used. Block = 256 thr = 4 waves;
// each wave computes a 16-row x 128-col strip with 32 MFMAs.
// Layouts (verified, learn_hip m89/m120): A[m=lane&15][k=quad*8+j],
// B[k=quad*8+j][n=lane&15], C/D col=lane&15 row=quad*4+reg.
__global__ __launch_bounds__(256, 2) void k_gemm_mfma(
    const unsigned short* __restrict__ Xb,
    const unsigned short* __restrict__ Wt,
    const float* __restrict__ bias,
    const float* __restrict__ dv,
    unsigned short* __restrict__ Y,
    int n) {
  const int lane = threadIdx.x & 63;
  const int wave = threadIdx.x >> 6;
  const int l15 = lane & 15;
  const int quad = lane >> 4;
  const int rbase = blockIdx.x * 64 + wave * 16;

  const bf16x8* W8 = (const bf16x8*)Wt;
  bf16x8 b[8][4];
#pragma unroll
  for (int ct = 0; ct < 8; ct++)
#pragma unroll
    for (int kc = 0; kc < 4; kc++)
      b[ct][kc] = W8[(ct * 16 + l15) * 16 + kc * 4 + quad];

  int row = rbase + l15;
  row = row < n ? row : n - 1;
  const bf16x8* X8 = (const bf16x8*)Xb;
  bf16x8 a[4];
#pragma unroll
  for (int kc = 0; kc < 4; kc++)
    a[kc] = X8[(size_t)row * 16 + kc * 4 + quad];

  floatx4 acc[8];
#pragma unroll
  for (int ct = 0; ct < 8; ct++) acc[ct] = (floatx4){0.f, 0.f, 0.f, 0.f};

#pragma unroll
  for (int kc = 0; kc < 4; kc++)
#pragma unroll
    for (int ct = 0; ct < 8; ct++)
      acc[ct] = __builtin_amdgcn_mfma_f32_16x16x32_bf16(a[kc], b[ct][kc], acc[ct], 0, 0, 0);

  const int orow = rbase + quad * 4;
  float4 dvv;
  dvv.x = 1.f; dvv.y = 1.f; dvv.z = 1.f; dvv.w = 1.f;
  if (dv) {
    int od = orow < n ? orow : 0;      // orow is 4-aligned, n % 4 == 0
    dvv = *(const float4*)(dv + od);
  }
#pragma unroll
  for (int ct = 0; ct < 8; ct++) {
    const int c = ct * 16 + l15;
    const float bv = bias ? bias[c] : 0.f;
#pragma unroll
    for (int r4 = 0; r4 < 4; r4++) {
      int r = orow + r4;
      float dm = r4 == 0 ? dvv.x : r4 == 1 ? dvv.y : r4 == 2 ? dvv.z : dvv.w;
      if (r < n) Y[(size_t)r * 128 + c] = f2bs(acc[ct][r4] * dm + bv);
    }
  }
}

// ---------------- aggregation (FINAL form — R15-proven, do not widen) ------
// FOUR nodes per wave: 16-lane quarter-waves each own a node; lane covers
// 8 bf16 cols as one uint4 (16 B). epk entries are 4 B src indices into the
// PRE-SCALED A (A[s] = dinv[s] * h[s]); no per-edge weight. Fixed stride 32,
// 8-padded with zero-row N. Nodes with degree > 32 additionally walk the
// (tiny) overflow list. R12: deeper single chain re-serialized (VGPR 36);
// R16: two-node version spilled (VGPR 64, WRITE x9, 2.2x slower). 8-deep /
// VGPR-36 is the practical optimum for this gather (~3.9 TB/s path).
static __device__ __forceinline__ void add8(uint4 h, float* a) {
  a[0] += bf_lo(h.x); a[1] += bf_hi(h.x);
  a[2] += bf_lo(h.y); a[3] += bf_hi(h.y);
  a[4] += bf_lo(h.z); a[5] += bf_hi(h.z);
  a[6] += bf_lo(h.w); a[7] += bf_hi(h.w);
}

__global__ __launch_bounds__(256, 4) void k_agg(
    const uint4* __restrict__ H,         // bf16x8 per lane [(n+1)*16], prescaled
    const int* __restrict__ cnt,
    const int* __restrict__ epk,
    const float* __restrict__ dinv,
    const float* __restrict__ bias,
    const uint4* __restrict__ resid,     // bf16x8 or null
    uint4* __restrict__ outb,            // bf16 out (layers 0,1) or null
    float4* __restrict__ outf,           // f32 out (layer 2) or null
    const int2* __restrict__ ovf, const int* __restrict__ ovfn,
    int n, int Ecap) {
  int node = blockIdx.x * 16 + (threadIdx.x >> 4);
  int l = threadIdx.x & 15;
  if (node >= n) return;

  int tot = cnt[node];
  int cm = tot < 32 ? tot : 32;
  int pdeg = (cm + 7) & ~7;

  uint4 hv = H[(size_t)node * 16 + l];   // self term (prescaled)
  float a[8];
  a[0] = bf_lo(hv.x); a[1] = bf_hi(hv.x);
  a[2] = bf_lo(hv.y); a[3] = bf_hi(hv.y);
  a[4] = bf_lo(hv.z); a[5] = bf_hi(hv.z);
  a[6] = bf_lo(hv.w); a[7] = bf_hi(hv.w);

  const int4* epk4 = (const int4*)(epk + (size_t)node * 32);
  for (int j = 0; j < pdeg; j += 8) {
    int4 e0 = epk4[j >> 2];
    int4 e1 = epk4[(j >> 2) + 1];
    uint4 h0 = H[(size_t)(unsigned)e0.x * 16 + l];
    uint4 h1 = H[(size_t)(unsigned)e0.y * 16 + l];
    uint4 h2 = H[(size_t)(unsigned)e0.z * 16 + l];
    uint4 h3 = H[(size_t)(unsigned)e0.w * 16 + l];
    uint4 h4 = H[(size_t)(unsigned)e1.x * 16 + l];
    uint4 h5 = H[(size_t)(unsigned)e1.y * 16 + l];
    uint4 h6 = H[(size_t)(unsigned)e1.z * 16 + l];
    uint4 h7 = H[(size_t)(unsigned)e1.w * 16 + l];
    add8(h0, a); add8(h1, a); add8(h2, a); add8(h3, a);
    add8(h4, a); add8(h5, a); add8(h6, a); add8(h7, a);
  }
  if (tot > 32) {                        // rare: walk overflow list
    int no = *ovfn;
    no = no < Ecap ? no : Ecap;          // defensive clamp
    for (int i = 0; i < no; i++) {
      int2 t = ovf[i];
      if (t.y == node) add8(H[(size_t)(unsigned)t.x * 16 + l], a);
    }
  }

  float dn = dinv[node];
  float4 bl = ((const float4*)bias)[l * 2];
  float4 bh = ((const float4*)bias)[l * 2 + 1];
  a[0] = fmaxf(fmaf(a[0], dn, bl.x), 0.f); a[1] = fmaxf(fmaf(a[1], dn, bl.y), 0.f);
  a[2] = fmaxf(fmaf(a[2], dn, bl.z), 0.f); a[3] = fmaxf(fmaf(a[3], dn, bl.w), 0.f);
  a[4] = fmaxf(fmaf(a[4], dn, bh.x), 0.f); a[5] = fmaxf(fmaf(a[5], dn, bh.y), 0.f);
  a[6] = fmaxf(fmaf(a[6], dn, bh.z), 0.f); a[7] = fmaxf(fmaf(a[7], dn, bh.w), 0.f);
  if (resid) {
    uint4 r = resid[(size_t)node * 16 + l];
    a[0] += bf_lo(r.x); a[1] += bf_hi(r.x);
    a[2] += bf_lo(r.y); a[3] += bf_hi(r.y);
    a[4] += bf_lo(r.z); a[5] += bf_hi(r.z);
    a[6] += bf_lo(r.w); a[7] += bf_hi(r.w);
  }
  if (outb) {
    uint4 o;
    o.x = pack2(a[0], a[1]); o.y = pack2(a[2], a[3]);
    o.z = pack2(a[4], a[5]); o.w = pack2(a[6], a[7]);
    outb[(size_t)node * 16 + l] = o;
  } else {
    float4 o0; o0.x = a[0]; o0.y = a[1]; o0.z = a[2]; o0.w = a[3];
    float4 o1; o1.x = a[4]; o1.y = a[5]; o1.z = a[6]; o1.w = a[7];
    outf[(size_t)node * 32 + l * 2] = o0;
    outf[(size_t)node * 32 + l * 2 + 1] = o1;
  }
}

extern "C" void kernel_launch(void* const* d_in, const int* in_sizes, int n_in,
                              void* d_out, int out_size, void* d_ws, size_t ws_size,
                              hipStream_t stream) {
  const float* x  = (const float*)d_in[0];
  const int* edges = (const int*)d_in[1];
  const float* W0 = (const float*)d_in[2];
  const float* b0 = (const float*)d_in[3];
  const float* W1 = (const float*)d_in[4];
  const float* b1 = (const float*)d_in[5];
  const float* W2 = (const float*)d_in[6];
  const float* b2 = (const float*)d_in[7];
  const float* Wr = (const float*)d_in[8];
  const float* br = (const float*)d_in[9];

  int N = in_sizes[0] / 128;
  int E = in_sizes[1] / 2;
  const int* src = edges;
  const int* dst = edges + E;

  char* ws = (char*)d_ws;
  size_t off = 0;
  auto alloc = [&](size_t bytes) -> void* {
    void* p = ws + off; off = WS_ALIGN(off + bytes); return p;
  };
  int*   cnt  = (int*)  alloc((size_t)N * 4);
  float* dinv = (float*)alloc((size_t)N * 4);
  int*   ovfn = (int*)  alloc(256);
  int2*  ovf  = (int2*) alloc((size_t)E * 8);
  int*   epk  = (int*)  alloc((size_t)N * 32 * 4);           // fixed-stride CSR
  unsigned short* xb = (unsigned short*)alloc((size_t)N * 128 * 2);
  unsigned short* Wt = (unsigned short*)alloc((size_t)4 * 16384 * 2);
  unsigned short* A  = (unsigned short*)alloc(((size_t)N + 1) * 128 * 2); // +zero row
  unsigned short* Hb = (unsigned short*)alloc((size_t)N * 128 * 2);
  unsigned short* R  = (unsigned short*)alloc((size_t)N * 128 * 2);
  int* pos = (int*)A;   // pos[E] lives only between k_cnt and k_scat; A is
                        // first written by GEMM0, which runs after k_scat.
  (void)ws_size; (void)n_in; (void)out_size;

  // ---- prep ----
  int n4 = N * 128 / 4;
  int zb = (N + 255) / 256;
  int xbn = (n4 + 255) / 256;
  k_prep<<<zb + xbn + 257, 256, 0, stream>>>(x, (unsigned*)xb, n4, cnt, N,
                                             W0, W1, W2, Wr, Wt, A, ovfn, zb, xbn);

  // ---- CSR build: atomic pass | residual GEMM | atomic-free scatter ----
  int gb = (N + 63) / 64;
  int eb = (E + 255) / 256;
  unsigned short* Wt0 = Wt;
  unsigned short* Wt1 = Wt + 16384;
  unsigned short* Wt2 = Wt + 2 * 16384;
  unsigned short* Wtr = Wt + 3 * 16384;
  k_cnt<<<eb, 256, 0, stream>>>(dst, E, cnt, pos);
  k_gemm_mfma<<<gb, 256, 0, stream>>>(xb, Wtr, br, nullptr, R, N);   // residual
  k_scat<<<eb, 256, 0, stream>>>(src, dst, pos, E, epk, ovf, ovfn);
  k_aux<<<(N + 255) / 256, 256, 0, stream>>>(cnt, dinv, epk, N);

  // ---- GCN layers (GEMMs prescale rows by dinv) ----
  int ab = (N + 15) / 16;   // 16 nodes (quarter-waves) per 256-thread block

  k_gemm_mfma<<<gb, 256, 0, stream>>>(xb, Wt0, nullptr, dinv, A, N);
  k_agg<<<ab, 256, 0, stream>>>((const uint4*)A, cnt, epk, dinv, b0,
                                (const uint4*)R, (uint4*)Hb, nullptr, ovf, ovfn, N, E);
  k_gemm_mfma<<<gb, 256, 0, stream>>>(Hb, Wt1, nullptr, dinv, A, N);
  k_agg<<<ab, 256, 0, stream>>>((const uint4*)A, cnt, epk, dinv, b1,
                                nullptr, (uint4*)R, nullptr, ovf, ovfn, N, E);
  k_gemm_mfma<<<gb, 256, 0, stream>>>(R, Wt2, nullptr, dinv, A, N);
  k_agg<<<ab, 256, 0, stream>>>((const uint4*)A, cnt, epk, dinv, b2,
                                nullptr, nullptr, (float4*)d_out, ovf, ovfn, N, E);
}

// Round 9
// 496.092 us; speedup vs baseline: 1.4707x; 1.1271x over previous
//
#include <hip/hip_runtime.h>
#include <hip/hip_bf16.h>
#include <cstdint>

// ---------------------------------------------------------------------------
// 3-layer GCN on MI355X — bf16 feature pipeline, f32 accumulate.
//   k_prep : x->bf16 | W->Wt bf16 | zero cnt, A zero-row, ovfn
//   k_cnt  : pos[e] = atomicAdd(cnt[dst[e]], 1)        (atomic pass, minimal)
//   k_gemm : R = bf16(xb@Wr + br)                      (residual)
//   k_scat : atomic-free scatter: rank<32 -> epk[d*32+rank]=src else ovf
//   k_aux  : dinv=rsqrt(cnt+1); pad epk slots [min(c,32), ceil8) with N.
//   A  = bf16( dinv * (xb @ W0) )    (dinv folded into GEMM epilogue)
//   H0 = bf16( relu(dinv_d * (A[self] + sum_src A[src]) + b0) + R )
//   ... layers 1,2 same; layer 2 writes f32 to d_out.
//
// Lessons: R10-12 — atomics execute memory-side regardless of scope; k_agg
// FETCH == 8 XCD x 25.6 MB (compulsory); single-chain ILP deepening gets
// re-serialized (VGPR stays 36). R15 — scatter fused into the atomic pass
// doubles memory-side write traffic (67 -> 120 us). R16 — two-node k_agg
// SPILLED (VGPR 64, WRITE 25->229 MB): k_agg's 8-deep/VGPR-36 form is FINAL.
// R17 — de-LDS GEMM regressed ~17 us/GEMM: B-fragment reads stride 256 B
// between lanes -> 64 cache lines per instruction when issued to VMEM;
// fine from LDS (staged coalesced). CSR split GOOD: cnt 67 + scat <67 vs
// fill1p 120. R18 (this): restore LDS-staged GEMM (R15-exact), keep split.
// ---------------------------------------------------------------------------

#define WS_ALIGN(x) (((x) + 255) & ~(size_t)255)

typedef __bf16 bf16x8 __attribute__((ext_vector_type(8)));
typedef float  floatx4 __attribute__((ext_vector_type(4)));

static __device__ __forceinline__ float bf_lo(unsigned u) {
  return __builtin_bit_cast(float, u << 16);
}
static __device__ __forceinline__ float bf_hi(unsigned u) {
  return __builtin_bit_cast(float, u & 0xffff0000u);
}
// f32 -> bf16 round-to-nearest-even (finite inputs only)
static __device__ __forceinline__ unsigned short f2bs(float f) {
  unsigned u = __builtin_bit_cast(unsigned, f);
  return (unsigned short)((u + 0x7fffu + ((u >> 16) & 1u)) >> 16);
}
static __device__ __forceinline__ unsigned pack2(float a, float b) {
  return (unsigned)f2bs(a) | ((unsigned)f2bs(b) << 16);
}

// ------- prep: zero cnt | x->bf16 | W->Wt bf16 | zero A row N | ovfn=0 -----
__global__ void k_prep(const float* __restrict__ x, unsigned* __restrict__ xb, int n4,
                       int* __restrict__ cnt, int n,
                       const float* __restrict__ W0, const float* __restrict__ W1,
                       const float* __restrict__ W2, const float* __restrict__ Wr,
                       unsigned short* __restrict__ Wt,
                       unsigned short* __restrict__ A, int* __restrict__ ovfn,
                       int zb, int xbn) {
  int b = blockIdx.x;
  if (b < zb) {
    int i = b * 256 + threadIdx.x;
    if (i < n) cnt[i] = 0;
  } else if (b < zb + xbn) {
    int i = (b - zb) * 256 + threadIdx.x;
    if (i < n4) {
      float4 v = ((const float4*)x)[i];
      uint2 o;
      o.x = pack2(v.x, v.y);
      o.y = pack2(v.z, v.w);
      ((uint2*)xb)[i] = o;
    }
  } else {
    int wb = b - zb - xbn;            // 0..256
    if (wb < 256) {
      int mat = wb >> 6, blk = wb & 63;
      const float* W = mat == 0 ? W0 : mat == 1 ? W1 : mat == 2 ? W2 : Wr;
      unsigned short* T = Wt + (size_t)mat * 16384;
      int i = blk * 256 + threadIdx.x;  // i = k*128 + nn, coalesced read
      int k = i >> 7, nn = i & 127;
      T[nn * 128 + k] = f2bs(W[i]);
    } else {
      // zero row N of A (pad-gather target) + overflow counter
      if (threadIdx.x < 16) {
        uint4 z; z.x = 0; z.y = 0; z.z = 0; z.w = 0;
        ((uint4*)(A + (size_t)n * 128))[threadIdx.x] = z;
      }
      if (threadIdx.x == 16) *ovfn = 0;
    }
  }
}

// ---- atomic pass only (proven shape): rank per edge, coalesced pos write ----
__global__ void k_cnt(const int* __restrict__ dstv, int E,
                      int* __restrict__ cnt, int* __restrict__ pos) {
  int e = blockIdx.x * blockDim.x + threadIdx.x;
  if (e < E) pos[e] = atomicAdd(&cnt[dstv[e]], 1);
}

// ---- atomic-free scatter (overflow path keeps its rare atomic) -------------
__global__ void k_scat(const int* __restrict__ srcv, const int* __restrict__ dstv,
                       const int* __restrict__ pos, int E,
                       int* __restrict__ epk, int2* __restrict__ ovf,
                       int* __restrict__ ovfn) {
  int e = blockIdx.x * blockDim.x + threadIdx.x;
  if (e < E) {
    int s = srcv[e], d = dstv[e];
    int r = pos[e];
    if (r < 32) {
      epk[(size_t)d * 32 + r] = s;
    } else {
      int o = atomicAdd(ovfn, 1);
      if (o < E) {                     // defensive clamp (can't exceed)
        int2 t; t.x = s; t.y = d;
        ovf[o] = t;
      }
    }
  }
}

// --------- aux: dinv from degree; pad epk slots with zero-row index --------
__global__ void k_aux(const int* __restrict__ cnt, float* __restrict__ dinv,
                      int* __restrict__ epk, int n) {
  int i = blockIdx.x * 256 + threadIdx.x;
  if (i < n) {
    int c = cnt[i];
    dinv[i] = rsqrtf((float)(c + 1));   // +1 = self-loop; always > 0
    int cm = c < 32 ? c : 32;
    int cp = (cm + 7) & ~7;
    for (int k = cm; k < cp; k++) epk[(size_t)i * 32 + k] = n;  // zero row
  }
}

// ---------------- bf16 MFMA GEMM: Y = bf16( dv[r] * (Xb@W) + bias ) --------
// Wt pre-transposed [n][k] bf16, staged in 32 KB LDS (coalesced once per
// block; the 256 B-stride B-fragment reads then hit LDS, not VMEM — R17
// showed issuing them to global costs ~17 us/GEMM). Block = 256 thr =
// 4 waves; each wave computes a 16-row x 128-col strip with 32 MFMAs.
// Layouts (verified, learn_hip m89/m120): A[m=lane&15][k=quad*8+j],
// B[k=quad*8+j][n=lane&15], C/D col=lane&15 row=quad*4+reg.
__global__ __launch_bounds__(256, 2) void k_gemm_mfma(
    const unsigned short* __restrict__ Xb,
    const unsigned short* __restrict__ Wt,
    const float* __restrict__ bias,
    const float* __restrict__ dv,
    unsigned short* __restrict__ Y,
    int n) {
  __shared__ unsigned short sWt[128 * 128];
  {
    const uint4* s4 = (const uint4*)Wt;
    uint4* d4 = (uint4*)sWt;
    for (int i = threadIdx.x; i < 2048; i += 256) d4[i] = s4[i];
  }
  __syncthreads();

  const int lane = threadIdx.x & 63;
  const int wave = threadIdx.x >> 6;
  const int l15 = lane & 15;
  const int quad = lane >> 4;
  const int rbase = blockIdx.x * 64 + wave * 16;

  const bf16x8* sW8 = (const bf16x8*)sWt;
  bf16x8 b[8][4];
#pragma unroll
  for (int ct = 0; ct < 8; ct++)
#pragma unroll
    for (int kc = 0; kc < 4; kc++)
      b[ct][kc] = sW8[(ct * 16 + l15) * 16 + kc * 4 + quad];

  int row = rbase + l15;
  row = row < n ? row : n - 1;
  const bf16x8* X8 = (const bf16x8*)Xb;
  bf16x8 a[4];
#pragma unroll
  for (int kc = 0; kc < 4; kc++)
    a[kc] = X8[(size_t)row * 16 + kc * 4 + quad];

  floatx4 acc[8];
#pragma unroll
  for (int ct = 0; ct < 8; ct++) acc[ct] = (floatx4){0.f, 0.f, 0.f, 0.f};

#pragma unroll
  for (int kc = 0; kc < 4; kc++)
#pragma unroll
    for (int ct = 0; ct < 8; ct++)
      acc[ct] = __builtin_amdgcn_mfma_f32_16x16x32_bf16(a[kc], b[ct][kc], acc[ct], 0, 0, 0);

  const int orow = rbase + quad * 4;
  float4 dvv;
  dvv.x = 1.f; dvv.y = 1.f; dvv.z = 1.f; dvv.w = 1.f;
  if (dv) {
    int od = orow < n ? orow : 0;      // orow is 4-aligned, n % 4 == 0
    dvv = *(const float4*)(dv + od);
  }
#pragma unroll
  for (int ct = 0; ct < 8; ct++) {
    const int c = ct * 16 + l15;
    const float bv = bias ? bias[c] : 0.f;
#pragma unroll
    for (int r4 = 0; r4 < 4; r4++) {
      int r = orow + r4;
      float dm = r4 == 0 ? dvv.x : r4 == 1 ? dvv.y : r4 == 2 ? dvv.z : dvv.w;
      if (r < n) Y[(size_t)r * 128 + c] = f2bs(acc[ct][r4] * dm + bv);
    }
  }
}

// ---------------- aggregation (FINAL form — R15-proven, do not widen) ------
// FOUR nodes per wave: 16-lane quarter-waves each own a node; lane covers
// 8 bf16 cols as one uint4 (16 B). epk entries are 4 B src indices into the
// PRE-SCALED A (A[s] = dinv[s] * h[s]); no per-edge weight. Fixed stride 32,
// 8-padded with zero-row N. Nodes with degree > 32 additionally walk the
// (tiny) overflow list. R12: deeper single chain re-serialized (VGPR 36);
// R16: two-node version spilled (VGPR 64, WRITE x9, 2.2x slower). 8-deep /
// VGPR-36 is the practical optimum for this gather (~3.9 TB/s path).
static __device__ __forceinline__ void add8(uint4 h, float* a) {
  a[0] += bf_lo(h.x); a[1] += bf_hi(h.x);
  a[2] += bf_lo(h.y); a[3] += bf_hi(h.y);
  a[4] += bf_lo(h.z); a[5] += bf_hi(h.z);
  a[6] += bf_lo(h.w); a[7] += bf_hi(h.w);
}

__global__ __launch_bounds__(256, 4) void k_agg(
    const uint4* __restrict__ H,         // bf16x8 per lane [(n+1)*16], prescaled
    const int* __restrict__ cnt,
    const int* __restrict__ epk,
    const float* __restrict__ dinv,
    const float* __restrict__ bias,
    const uint4* __restrict__ resid,     // bf16x8 or null
    uint4* __restrict__ outb,            // bf16 out (layers 0,1) or null
    float4* __restrict__ outf,           // f32 out (layer 2) or null
    const int2* __restrict__ ovf, const int* __restrict__ ovfn,
    int n, int Ecap) {
  int node = blockIdx.x * 16 + (threadIdx.x >> 4);
  int l = threadIdx.x & 15;
  if (node >= n) return;

  int tot = cnt[node];
  int cm = tot < 32 ? tot : 32;
  int pdeg = (cm + 7) & ~7;

  uint4 hv = H[(size_t)node * 16 + l];   // self term (prescaled)
  float a[8];
  a[0] = bf_lo(hv.x); a[1] = bf_hi(hv.x);
  a[2] = bf_lo(hv.y); a[3] = bf_hi(hv.y);
  a[4] = bf_lo(hv.z); a[5] = bf_hi(hv.z);
  a[6] = bf_lo(hv.w); a[7] = bf_hi(hv.w);

  const int4* epk4 = (const int4*)(epk + (size_t)node * 32);
  for (int j = 0; j < pdeg; j += 8) {
    int4 e0 = epk4[j >> 2];
    int4 e1 = epk4[(j >> 2) + 1];
    uint4 h0 = H[(size_t)(unsigned)e0.x * 16 + l];
    uint4 h1 = H[(size_t)(unsigned)e0.y * 16 + l];
    uint4 h2 = H[(size_t)(unsigned)e0.z * 16 + l];
    uint4 h3 = H[(size_t)(unsigned)e0.w * 16 + l];
    uint4 h4 = H[(size_t)(unsigned)e1.x * 16 + l];
    uint4 h5 = H[(size_t)(unsigned)e1.y * 16 + l];
    uint4 h6 = H[(size_t)(unsigned)e1.z * 16 + l];
    uint4 h7 = H[(size_t)(unsigned)e1.w * 16 + l];
    add8(h0, a); add8(h1, a); add8(h2, a); add8(h3, a);
    add8(h4, a); add8(h5, a); add8(h6, a); add8(h7, a);
  }
  if (tot > 32) {                        // rare: walk overflow list
    int no = *ovfn;
    no = no < Ecap ? no : Ecap;          // defensive clamp
    for (int i = 0; i < no; i++) {
      int2 t = ovf[i];
      if (t.y == node) add8(H[(size_t)(unsigned)t.x * 16 + l], a);
    }
  }

  float dn = dinv[node];
  float4 bl = ((const float4*)bias)[l * 2];
  float4 bh = ((const float4*)bias)[l * 2 + 1];
  a[0] = fmaxf(fmaf(a[0], dn, bl.x), 0.f); a[1] = fmaxf(fmaf(a[1], dn, bl.y), 0.f);
  a[2] = fmaxf(fmaf(a[2], dn, bl.z), 0.f); a[3] = fmaxf(fmaf(a[3], dn, bl.w), 0.f);
  a[4] = fmaxf(fmaf(a[4], dn, bh.x), 0.f); a[5] = fmaxf(fmaf(a[5], dn, bh.y), 0.f);
  a[6] = fmaxf(fmaf(a[6], dn, bh.z), 0.f); a[7] = fmaxf(fmaf(a[7], dn, bh.w), 0.f);
  if (resid) {
    uint4 r = resid[(size_t)node * 16 + l];
    a[0] += bf_lo(r.x); a[1] += bf_hi(r.x);
    a[2] += bf_lo(r.y); a[3] += bf_hi(r.y);
    a[4] += bf_lo(r.z); a[5] += bf_hi(r.z);
    a[6] += bf_lo(r.w); a[7] += bf_hi(r.w);
  }
  if (outb) {
    uint4 o;
    o.x = pack2(a[0], a[1]); o.y = pack2(a[2], a[3]);
    o.z = pack2(a[4], a[5]); o.w = pack2(a[6], a[7]);
    outb[(size_t)node * 16 + l] = o;
  } else {
    float4 o0; o0.x = a[0]; o0.y = a[1]; o0.z = a[2]; o0.w = a[3];
    float4 o1; o1.x = a[4]; o1.y = a[5]; o1.z = a[6]; o1.w = a[7];
    outf[(size_t)node * 32 + l * 2] = o0;
    outf[(size_t)node * 32 + l * 2 + 1] = o1;
  }
}

extern "C" void kernel_launch(void* const* d_in, const int* in_sizes, int n_in,
                              void* d_out, int out_size, void* d_ws, size_t ws_size,
                              hipStream_t stream) {
  const float* x  = (const float*)d_in[0];
  const int* edges = (const int*)d_in[1];
  const float* W0 = (const float*)d_in[2];
  const float* b0 = (const float*)d_in[3];
  const float* W1 = (const float*)d_in[4];
  const float* b1 = (const float*)d_in[5];
  const float* W2 = (const float*)d_in[6];
  const float* b2 = (const float*)d_in[7];
  const float* Wr = (const float*)d_in[8];
  const float* br = (const float*)d_in[9];

  int N = in_sizes[0] / 128;
  int E = in_sizes[1] / 2;
  const int* src = edges;
  const int* dst = edges + E;

  char* ws = (char*)d_ws;
  size_t off = 0;
  auto alloc = [&](size_t bytes) -> void* {
    void* p = ws + off; off = WS_ALIGN(off + bytes); return p;
  };
  int*   cnt  = (int*)  alloc((size_t)N * 4);
  float* dinv = (float*)alloc((size_t)N * 4);
  int*   ovfn = (int*)  alloc(256);
  int2*  ovf  = (int2*) alloc((size_t)E * 8);
  int*   epk  = (int*)  alloc((size_t)N * 32 * 4);           // fixed-stride CSR
  unsigned short* xb = (unsigned short*)alloc((size_t)N * 128 * 2);
  unsigned short* Wt = (unsigned short*)alloc((size_t)4 * 16384 * 2);
  unsigned short* A  = (unsigned short*)alloc(((size_t)N + 1) * 128 * 2); // +zero row
  unsigned short* Hb = (unsigned short*)alloc((size_t)N * 128 * 2);
  unsigned short* R  = (unsigned short*)alloc((size_t)N * 128 * 2);
  int* pos = (int*)A;   // pos[E] lives only between k_cnt and k_scat; A is
                        // first written by GEMM0, which runs after k_scat.
  (void)ws_size; (void)n_in; (void)out_size;

  // ---- prep ----
  int n4 = N * 128 / 4;
  int zb = (N + 255) / 256;
  int xbn = (n4 + 255) / 256;
  k_prep<<<zb + xbn + 257, 256, 0, stream>>>(x, (unsigned*)xb, n4, cnt, N,
                                             W0, W1, W2, Wr, Wt, A, ovfn, zb, xbn);

  // ---- CSR build: atomic pass | residual GEMM | atomic-free scatter ----
  int gb = (N + 63) / 64;
  int eb = (E + 255) / 256;
  unsigned short* Wt0 = Wt;
  unsigned short* Wt1 = Wt + 16384;
  unsigned short* Wt2 = Wt + 2 * 16384;
  unsigned short* Wtr = Wt + 3 * 16384;
  k_cnt<<<eb, 256, 0, stream>>>(dst, E, cnt, pos);
  k_gemm_mfma<<<gb, 256, 0, stream>>>(xb, Wtr, br, nullptr, R, N);   // residual
  k_scat<<<eb, 256, 0, stream>>>(src, dst, pos, E, epk, ovf, ovfn);
  k_aux<<<(N + 255) / 256, 256, 0, stream>>>(cnt, dinv, epk, N);

  // ---- GCN layers (GEMMs prescale rows by dinv) ----
  int ab = (N + 15) / 16;   // 16 nodes (quarter-waves) per 256-thread block

  k_gemm_mfma<<<gb, 256, 0, stream>>>(xb, Wt0, nullptr, dinv, A, N);
  k_agg<<<ab, 256, 0, stream>>>((const uint4*)A, cnt, epk, dinv, b0,
                                (const uint4*)R, (uint4*)Hb, nullptr, ovf, ovfn, N, E);
  k_gemm_mfma<<<gb, 256, 0, stream>>>(Hb, Wt1, nullptr, dinv, A, N);
  k_agg<<<ab, 256, 0, stream>>>((const uint4*)A, cnt, epk, dinv, b1,
                                nullptr, (uint4*)R, nullptr, ovf, ovfn, N, E);
  k_gemm_mfma<<<gb, 256, 0, stream>>>(R, Wt2, nullptr, dinv, A, N);
  k_agg<<<ab, 256, 0, stream>>>((const uint4*)A, cnt, epk, dinv, b2,
                                nullptr, nullptr, (float4*)d_out, ovf, ovfn, N, E);
}